// Round 3
// baseline (1420.974 us; speedup 1.0000x reference)
//
#include <hip/hip_runtime.h>

typedef unsigned short u16;
typedef __bf16 bf16x8 __attribute__((ext_vector_type(8)));
typedef u16 u16x8 __attribute__((ext_vector_type(8)));
typedef u16 u16x4 __attribute__((ext_vector_type(4)));
typedef float f32x4 __attribute__((ext_vector_type(4)));

__device__ __forceinline__ float bf2f(u16 v) {
    union { unsigned u; float f; } c; c.u = ((unsigned)v) << 16; return c.f;
}
__device__ __forceinline__ u16 f2bf(float f) {
    union { float f; unsigned u; } c; c.f = f;
    unsigned u = c.u;
    unsigned r = (u + 0x7fffu + ((u >> 16) & 1u)) >> 16;
    return (u16)r;
}
// HW RNE f32->bf16 (single v_cvt, same rounding as f2bf; scan hot paths only)
__device__ __forceinline__ u16 f2bf_h(float f) {
    __bf16 h = (__bf16)f;
    union { __bf16 h; u16 u; } c; c.h = h; return c.u;
}

// MFMA fragment load (works for LDS or global pointers): LEFT operand from
// [m][k] row-major, or RIGHT operand from [n][k] row-major.
// row = row0 + (lane&15), k = k0 + (lane>>4)*8 .. +8.
__device__ __forceinline__ bf16x8 ldfrag(const u16* base, int stride, int row0, int k0, int lane) {
    return *(const bf16x8*)(base + (size_t)(row0 + (lane & 15)) * stride + k0 + (lane >> 4) * 8);
}

// Raw workgroup barrier: commits LDS (lgkmcnt only) but does NOT drain vmcnt,
// so cross-chunk global prefetches stay in flight (counted-vmcnt pattern).
__device__ __forceinline__ void block_barrier() {
    __builtin_amdgcn_sched_barrier(0);
    asm volatile("s_waitcnt lgkmcnt(0)");
    __builtin_amdgcn_s_barrier();
    __builtin_amdgcn_sched_barrier(0);
}

// ---------------------------------------------------------------------------
// fp32 -> bf16 elementwise convert
// ---------------------------------------------------------------------------
__global__ __launch_bounds__(256) void cvt_kernel(const float* __restrict__ src,
                                                  u16* __restrict__ dst) {
    const long i = ((long)blockIdx.x * 256 + threadIdx.x) * 4;
    f32x4 v = *(const f32x4*)(src + i);
    u16x4 o;
#pragma unroll
    for (int r = 0; r < 4; r++) o[r] = f2bf(v[r]);
    *(u16x4*)(dst + i) = o;
}

// ---------------------------------------------------------------------------
// Weight transpose + cvt: src fp32 [1024,1024] (k,n) -> dst bf16 (n,k)
// ---------------------------------------------------------------------------
__global__ __launch_bounds__(256) void transpose_kernel(const float* __restrict__ src,
                                                        u16* __restrict__ dst) {
    __shared__ float tile[32][33];
    const int n0 = blockIdx.x * 32, k0 = blockIdx.y * 32;
    const int tx = threadIdx.x, ty = threadIdx.y;   // 32 x 8
#pragma unroll
    for (int i = 0; i < 32; i += 8)
        tile[ty + i][tx] = src[(long)(k0 + ty + i) * 1024 + n0 + tx];
    __syncthreads();
#pragma unroll
    for (int i = 0; i < 32; i += 8)
        dst[(long)(n0 + ty + i) * 1024 + k0 + tx] = f2bf(tile[tx][ty + i]);
}

// ---------------------------------------------------------------------------
// MFMA GEMM: C[M,N] = A[M,K](bf16) * BT[N,K](bf16)^T, fp32 accum.
// ---------------------------------------------------------------------------
#define LDK 40

template <int F32OUT>
__global__ __launch_bounds__(256) void gemm_kernel(const u16* __restrict__ A,
                                                   const u16* __restrict__ BT,
                                                   void* __restrict__ Cv,
                                                   int M, int N, int K, int ldc) {
    __shared__ u16 As[128][LDK];
    __shared__ u16 Bs[128][LDK];
    const int tid  = threadIdx.x;
    const int lane = tid & 63;
    const int wave = tid >> 6;
    const int wm   = (wave >> 1) * 64;
    const int wn   = (wave & 1) * 64;
    const long m0  = (long)blockIdx.y * 128;
    const long n0  = (long)blockIdx.x * 128;

    const f32x4 zero = {0.f, 0.f, 0.f, 0.f};
    f32x4 acc[4][4];
#pragma unroll
    for (int i = 0; i < 4; i++)
#pragma unroll
        for (int j = 0; j < 4; j++) acc[i][j] = zero;

    const int r0 = tid >> 2;
    const int c0 = (tid & 3) * 8;
    const u16* Ag = A + (m0 + r0) * K + c0;
    const u16* Bg = BT + (n0 + r0) * K + c0;

    for (int k0 = 0; k0 < K; k0 += 32) {
        u16x8 a0 = *(const u16x8*)(Ag + k0);
        u16x8 a1 = *(const u16x8*)(Ag + (long)64 * K + k0);
        u16x8 b0 = *(const u16x8*)(Bg + k0);
        u16x8 b1 = *(const u16x8*)(Bg + (long)64 * K + k0);
        *(u16x8*)(&As[r0][c0])      = a0;
        *(u16x8*)(&As[r0 + 64][c0]) = a1;
        *(u16x8*)(&Bs[r0][c0])      = b0;
        *(u16x8*)(&Bs[r0 + 64][c0]) = b1;
        __syncthreads();
        const int qk = (lane >> 4) * 8;
        const int mr = lane & 15;
        bf16x8 af[4], bfr[4];
#pragma unroll
        for (int i = 0; i < 4; i++) af[i]  = *(const bf16x8*)(&As[wm + i * 16 + mr][qk]);
#pragma unroll
        for (int j = 0; j < 4; j++) bfr[j] = *(const bf16x8*)(&Bs[wn + j * 16 + mr][qk]);
#pragma unroll
        for (int i = 0; i < 4; i++)
#pragma unroll
            for (int j = 0; j < 4; j++)
                acc[i][j] = __builtin_amdgcn_mfma_f32_16x16x32_bf16(af[i], bfr[j], acc[i][j], 0, 0, 0);
        __syncthreads();
    }

    const int cr = (lane >> 4) * 4;
    const int cc = lane & 15;
#pragma unroll
    for (int i = 0; i < 4; i++) {
#pragma unroll
        for (int j = 0; j < 4; j++) {
            const long m = m0 + wm + i * 16 + cr;
            const long n = n0 + wn + j * 16 + cc;
            if (F32OUT) {
                float* C = (float*)Cv;
#pragma unroll
                for (int r = 0; r < 4; r++) C[(m + r) * ldc + n] = acc[i][j][r];
            } else {
                u16* C = (u16*)Cv;
#pragma unroll
                for (int r = 0; r < 4; r++) C[(m + r) * ldc + n] = f2bf(acc[i][j][r]);
            }
        }
    }
}

// ---------------------------------------------------------------------------
// Same GEMM but A operand is fp32 in global (converted to bf16 at staging).
// ---------------------------------------------------------------------------
__global__ __launch_bounds__(256) void gemm_a32_kernel(const float* __restrict__ A,
                                                       const u16* __restrict__ BT,
                                                       u16* __restrict__ C,
                                                       int M, int N, int K, int ldc) {
    __shared__ u16 As[128][LDK];
    __shared__ u16 Bs[128][LDK];
    const int tid  = threadIdx.x;
    const int lane = tid & 63;
    const int wave = tid >> 6;
    const int wm   = (wave >> 1) * 64;
    const int wn   = (wave & 1) * 64;
    const long m0  = (long)blockIdx.y * 128;
    const long n0  = (long)blockIdx.x * 128;

    const f32x4 zero = {0.f, 0.f, 0.f, 0.f};
    f32x4 acc[4][4];
#pragma unroll
    for (int i = 0; i < 4; i++)
#pragma unroll
        for (int j = 0; j < 4; j++) acc[i][j] = zero;

    const int r0 = tid >> 2;
    const int c0 = (tid & 3) * 8;
    const float* Ag = A + (m0 + r0) * K + c0;
    const u16* Bg = BT + (n0 + r0) * K + c0;

    for (int k0 = 0; k0 < K; k0 += 32) {
        f32x4 af0 = *(const f32x4*)(Ag + k0);
        f32x4 af1 = *(const f32x4*)(Ag + k0 + 4);
        f32x4 ag0 = *(const f32x4*)(Ag + (long)64 * K + k0);
        f32x4 ag1 = *(const f32x4*)(Ag + (long)64 * K + k0 + 4);
        u16x8 b0 = *(const u16x8*)(Bg + k0);
        u16x8 b1 = *(const u16x8*)(Bg + (long)64 * K + k0);
        u16x8 a0, a1;
#pragma unroll
        for (int r = 0; r < 4; r++) {
            a0[r] = f2bf(af0[r]); a0[r + 4] = f2bf(af1[r]);
            a1[r] = f2bf(ag0[r]); a1[r + 4] = f2bf(ag1[r]);
        }
        *(u16x8*)(&As[r0][c0])      = a0;
        *(u16x8*)(&As[r0 + 64][c0]) = a1;
        *(u16x8*)(&Bs[r0][c0])      = b0;
        *(u16x8*)(&Bs[r0 + 64][c0]) = b1;
        __syncthreads();
        const int qk = (lane >> 4) * 8;
        const int mr = lane & 15;
        bf16x8 af[4], bfr[4];
#pragma unroll
        for (int i = 0; i < 4; i++) af[i]  = *(const bf16x8*)(&As[wm + i * 16 + mr][qk]);
#pragma unroll
        for (int j = 0; j < 4; j++) bfr[j] = *(const bf16x8*)(&Bs[wn + j * 16 + mr][qk]);
#pragma unroll
        for (int i = 0; i < 4; i++)
#pragma unroll
            for (int j = 0; j < 4; j++)
                acc[i][j] = __builtin_amdgcn_mfma_f32_16x16x32_bf16(af[i], bfr[j], acc[i][j], 0, 0, 0);
        __syncthreads();
    }

    const int cr = (lane >> 4) * 4;
    const int cc = lane & 15;
#pragma unroll
    for (int i = 0; i < 4; i++) {
#pragma unroll
        for (int j = 0; j < 4; j++) {
            const long m = m0 + wm + i * 16 + cr;
            const long n = n0 + wn + j * 16 + cc;
#pragma unroll
            for (int r = 0; r < 4; r++) C[(m + r) * ldc + n] = f2bf(acc[i][j][r]);
        }
    }
}

// ---------------------------------------------------------------------------
// Fused: in-place L2-normalize q (x 1/16) and k per head; beta & dec per head.
// ---------------------------------------------------------------------------
__global__ __launch_bounds__(1024) void norm_beta_kernel(
    const u16* __restrict__ xb, u16* __restrict__ Y,
    const float* __restrict__ Wb, const float* __restrict__ Wa,
    const float* __restrict__ A_log, const float* __restrict__ dt_bias,
    float* __restrict__ beta, float* __restrict__ dec) {
    const long row = blockIdx.x;
    const int c = threadIdx.x;
    const int h = c >> 8;
    float qv = bf2f(Y[row * 3072 + c]);
    float kv = bf2f(Y[row * 3072 + 1024 + c]);
    float xv = bf2f(xb[row * 1024 + c]);
    float vals[10];
    vals[0] = qv * qv;
    vals[1] = kv * kv;
#pragma unroll
    for (int hh = 0; hh < 4; hh++) vals[2 + hh] = xv * Wb[c * 4 + hh];
#pragma unroll
    for (int hh = 0; hh < 4; hh++) vals[6 + hh] = xv * Wa[c * 4 + hh];
#pragma unroll
    for (int i = 0; i < 10; i++)
        for (int off = 32; off; off >>= 1) vals[i] += __shfl_xor(vals[i], off, 64);

    __shared__ float wred[16][10];
    __shared__ float sQ[4], sK[4];
    const int w = c >> 6;
    if ((c & 63) == 0) {
#pragma unroll
        for (int i = 0; i < 10; i++) wred[w][i] = vals[i];
    }
    __syncthreads();
    if (c < 4) {
        float s = wred[c * 4 + 0][0] + wred[c * 4 + 1][0] + wred[c * 4 + 2][0] + wred[c * 4 + 3][0];
        sQ[c] = rsqrtf(s + 1e-6f) * 0.0625f;
    } else if (c < 8) {
        int hh = c - 4;
        float s = wred[hh * 4 + 0][1] + wred[hh * 4 + 1][1] + wred[hh * 4 + 2][1] + wred[hh * 4 + 3][1];
        sK[hh] = rsqrtf(s + 1e-6f);
    } else if (c < 12) {
        int hh = c - 8;
        float s = 0.f;
        for (int ww = 0; ww < 16; ww++) s += wred[ww][2 + hh];
        beta[row * 4 + hh] = 1.f / (1.f + expf(-s));
    } else if (c < 16) {
        int hh = c - 12;
        float s = 0.f;
        for (int ww = 0; ww < 16; ww++) s += wred[ww][6 + hh];
        float z = s + dt_bias[hh];
        float sp = (z > 0.f) ? (z + log1pf(expf(-z))) : log1pf(expf(z));
        dec[row * 4 + hh] = expf(-expf(A_log[hh]) * sp);
    }
    __syncthreads();
    Y[row * 3072 + c]        = f2bf(qv * sQ[h]);
    Y[row * 3072 + 1024 + c] = f2bf(kv * sK[h]);
}

// ---------------------------------------------------------------------------
// PASS A (chunk-parallel prep): per (bh, chunk) compute A matrix, T=(I+A)^-1
// via nilpotent doubling, and M matrix. Writes T, M (bf16 [64][64]) to global.
// Also writes the per-chunk scalar tables sfg[bh*64+c][256]:
//   [0:64)=gam  [64:128)=beta*gam  [128:192)=beta  [192:256)=ksc (gamL/gam)
// ---------------------------------------------------------------------------
__global__ __launch_bounds__(256) void prep_kernel(const u16* __restrict__ Y,
                                                   const float* __restrict__ beta,
                                                   const float* __restrict__ dec,
                                                   u16* __restrict__ Tg,
                                                   u16* __restrict__ Mg,
                                                   float* __restrict__ sfg) {
    __shared__ __attribute__((aligned(16))) u16 lds[38400];
    __shared__ float sf[320];
    u16* KS  = lds;            // 64 x 264
    u16* QS  = lds + 16896;    // 64 x 264
    u16* AM  = lds + 33792;    // 64 x 72
    // overlays (valid after G phase; KS/QS dead):
    u16* Tm  = lds;            // 64 x 72
    u16* AMT = lds + 4608;
    u16* MP  = lds + 9216;
    u16* MPT = lds + 13824;

    const int bx = blockIdx.x;
    const int bh = bx >> 6, c = bx & 63;
    const int b = bh >> 2, h = bh & 3;
    const int tid = threadIdx.x, lane = tid & 63, wv = tid >> 6;
    const int quad = lane >> 4, l15 = lane & 15;
    const int tld = tid >> 2, seg = tid & 3;
    const long bt0 = (long)b * 4096 + c * 64;
    u16* Tc = Tg + (size_t)(bh * 64 + c) * 4096;
    u16* Mc = Mg + (size_t)(bh * 64 + c) * 4096;
    const f32x4 z4 = {0.f, 0.f, 0.f, 0.f};

    // ---- stage K,Q; gamma prefix ----
    {
        const long rb = (bt0 + tld) * 3072 + h * 256 + seg * 64;
#pragma unroll
        for (int i = 0; i < 8; i++) {
            *(u16x8*)&KS[tld * 264 + seg * 64 + i * 8] = *(const u16x8*)&Y[rb + 1024 + i * 8];
            *(u16x8*)&QS[tld * 264 + seg * 64 + i * 8] = *(const u16x8*)&Y[rb + i * 8];
        }
    }
    if (wv == 0) {
        float d   = dec [(bt0 + lane) * 4 + h];
        float bt_ = beta[(bt0 + lane) * 4 + h];
        float lg = log2f(fmaxf(d, 1e-30f));
#pragma unroll
        for (int off = 1; off < 64; off <<= 1) {
            float o = __shfl_up(lg, off, 64);
            if (lane >= off) lg += o;
        }
        sf[lane] = lg; sf[192 + lane] = bt_;
        float lgL = __shfl(lg, 63, 64);
        float g = exp2f(lg);
        float* sfc = sfg + (size_t)(bh * 64 + c) * 256;
        sfc[lane]       = g;
        sfc[64 + lane]  = bt_ * g;
        sfc[128 + lane] = bt_;
        sfc[192 + lane] = exp2f(lgL - lg);
    }
    __syncthreads();   // B1

    // ---- G phase: waves 0-1 -> A matrix (LDS); waves 2-3 -> M (global) ----
    {
        const u16* Ab = (wv < 2) ? KS : QS;
        const int mb = (wv & 1) * 32;
        f32x4 g[2][4];
#pragma unroll
        for (int mi = 0; mi < 2; mi++)
#pragma unroll
            for (int sj = 0; sj < 4; sj++) g[mi][sj] = z4;
#pragma unroll 2
        for (int k0 = 0; k0 < 256; k0 += 32) {
            bf16x8 bfr[4];
#pragma unroll
            for (int sj = 0; sj < 4; sj++) bfr[sj] = ldfrag(KS, 264, sj * 16, k0, lane);
#pragma unroll
            for (int mi = 0; mi < 2; mi++) {
                bf16x8 af = ldfrag(Ab, 264, mb + mi * 16, k0, lane);
#pragma unroll
                for (int sj = 0; sj < 4; sj++)
                    g[mi][sj] = __builtin_amdgcn_mfma_f32_16x16x32_bf16(af, bfr[sj], g[mi][sj], 0, 0, 0);
            }
        }
#pragma unroll
        for (int mi = 0; mi < 2; mi++)
#pragma unroll
            for (int sj = 0; sj < 4; sj++)
#pragma unroll
                for (int r = 0; r < 4; r++) {
                    const int t_ = mb + mi * 16 + quad * 4 + r, s_ = sj * 16 + l15;
                    if (wv < 2)
                        AM[t_ * 72 + s_] = (s_ < t_) ? f2bf(sf[192 + t_] * exp2f(sf[t_] - sf[s_]) * g[mi][sj][r]) : (u16)0;
                    else
                        Mc[t_ * 64 + s_] = (s_ <= t_) ? f2bf(exp2f(sf[t_] - sf[s_]) * g[mi][sj][r]) : (u16)0;
                }
    }
    __syncthreads();   // B2 (KS/QS dead)

    // ---- solve init: T = I - A, A^T ----
    {
        const int t_ = tid >> 2;
#pragma unroll
        for (int i = 0; i < 16; i++) {
            const int s_ = (tid & 3) * 16 + i;
            const u16 a = AM[t_ * 72 + s_];
            Tm[t_ * 72 + s_] = (t_ == s_) ? (u16)0x3F80 : (u16)(a ^ 0x8000);
            AMT[s_ * 72 + t_] = a;
        }
    }
    __syncthreads();   // B3

    // ---- r1: Mp = N*N ----
    {
        f32x4 sq[4];
#pragma unroll
        for (int sj = 0; sj < 4; sj++) sq[sj] = z4;
#pragma unroll
        for (int k0 = 0; k0 < 64; k0 += 32) {
            bf16x8 a = ldfrag(AM, 72, 16 * wv, k0, lane);
#pragma unroll
            for (int sj = 0; sj < 4; sj++) {
                bf16x8 bb = ldfrag(AMT, 72, sj * 16, k0, lane);
                sq[sj] = __builtin_amdgcn_mfma_f32_16x16x32_bf16(a, bb, sq[sj], 0, 0, 0);
            }
        }
#pragma unroll
        for (int sj = 0; sj < 4; sj++)
#pragma unroll
            for (int r = 0; r < 4; r++) {
                const int t_ = 16 * wv + quad * 4 + r, s_ = sj * 16 + l15;
                const u16 vbf = f2bf(sq[sj][r]);
                MP[t_ * 72 + s_] = vbf;
                MPT[s_ * 72 + t_] = vbf;
            }
        __syncthreads();   // B4
    }

    // ---- fused rounds: T += T*Mp ; Mp <- Mp*Mp (skip on last) ----
#pragma unroll 1
    for (int jj = 0; jj < 5; jj++) {
        const bool last = (jj == 4);
        f32x4 pp[4], sq[4];
#pragma unroll
        for (int sj = 0; sj < 4; sj++) {
            sq[sj] = z4;
#pragma unroll
            for (int r = 0; r < 4; r++)
                pp[sj][r] = bf2f(Tm[(16 * wv + quad * 4 + r) * 72 + sj * 16 + l15]);
        }
#pragma unroll
        for (int k0 = 0; k0 < 64; k0 += 32) {
            bf16x8 at = ldfrag(Tm, 72, 16 * wv, k0, lane);
            bf16x8 am = ldfrag(MP, 72, 16 * wv, k0, lane);
#pragma unroll
            for (int sj = 0; sj < 4; sj++) {
                bf16x8 bb = ldfrag(MPT, 72, sj * 16, k0, lane);
                pp[sj] = __builtin_amdgcn_mfma_f32_16x16x32_bf16(at, bb, pp[sj], 0, 0, 0);
                if (!last) sq[sj] = __builtin_amdgcn_mfma_f32_16x16x32_bf16(am, bb, sq[sj], 0, 0, 0);
            }
        }
        __syncthreads();
#pragma unroll
        for (int sj = 0; sj < 4; sj++)
#pragma unroll
            for (int r = 0; r < 4; r++) {
                const int t_ = 16 * wv + quad * 4 + r, s_ = sj * 16 + l15;
                Tm[t_ * 72 + s_] = f2bf(pp[sj][r]);
                if (!last) {
                    const u16 vbf = f2bf(sq[sj][r]);
                    MP[t_ * 72 + s_] = vbf;
                    MPT[s_ * 72 + t_] = vbf;
                }
            }
        __syncthreads();
    }

    // ---- write T to global ----
    {
        const int t_ = tid >> 2;
#pragma unroll
        for (int i = 0; i < 16; i++) {
            const int s_ = (tid & 3) * 16 + i;
            Tc[t_ * 64 + s_] = Tm[t_ * 72 + s_];
        }
    }
}

// ---------------------------------------------------------------------------
// PASS B (sequential scan): grid 64 = bh(16) x dvs(4), 512 threads / 8 waves.
// R3: latency was the binding constraint (13K cy/chunk vs ~3K of work at
// 1 wave/SIMD). Split each phase by (t-group wq = wv&3) x (dv-half wh = wv>>2)
// -> per-wave work halves, 2 waves/SIMD interleave stalls. LDS + traffic
// unchanged; K/Q fragments duplicated across the wh pair (L1/L2 hits).
// 3 barriers/chunk. LDS 96 KB -> 1 block/CU.
// ---------------------------------------------------------------------------
struct KQfrag { bf16x8 ak[8]; bf16x8 aq[8]; };

__global__ __launch_bounds__(512, 1) void scan_kernel(const u16* __restrict__ Y,
                                                      const float* __restrict__ sfg,
                                                      const u16* __restrict__ Tg,
                                                      const u16* __restrict__ Mg,
                                                      u16* __restrict__ Ob) {
    __shared__ __attribute__((aligned(16))) u16 KT[4 * 4616];   // [panel][dk6*72 + t_rot]
    __shared__ __attribute__((aligned(16))) u16 ST[64 * 264];   // [dv][dk]
    __shared__ __attribute__((aligned(16))) u16 RHST[64 * 72];  // [dv][t]
    __shared__ __attribute__((aligned(16))) u16 UTp[64 * 72];   // [dv][t] plain
    __shared__ __attribute__((aligned(16))) u16 UTk[64 * 72];   // [dv][t] ksc-folded

    const int bx = blockIdx.x;
    const int bh = bx >> 2, dvs = bx & 3;
    const int b = bh >> 2, h = bh & 3;
    const int tid = threadIdx.x, lane = tid & 63, wv = tid >> 6;
    const int wq = wv & 3;           // t-group (16 t rows)
    const int wh = wv >> 2;          // dv-half (32 dv rows)
    const int quad = lane >> 4, l15 = lane & 15;
    const int tW = 16 * wq + l15;                     // lane's t (output col)
    const int tph = 16 * ((wq + quad) & 3) + l15;     // rotated t for KT writes
    int toff[4];                                      // KT read t-rotation per dk-tile
#pragma unroll
    for (int j = 0; j < 4; j++) toff[j] = ((((j << 1) + (l15 >> 3)) & 3) << 4);
    const f32x4 z4 = {0.f, 0.f, 0.f, 0.f};

    f32x4 Sacc[2][4];   // [dv-tile in wh half][dk-tile in wq slice]
#pragma unroll
    for (int i = 0; i < 2; i++)
#pragma unroll
        for (int j = 0; j < 4; j++) Sacc[i][j] = z4;
    for (int i = tid; i < 64 * 264; i += 512) ST[i] = 0;
    __syncthreads();

    KQfrag R0, R1;
    {
        const u16* Kg = Y + ((long)b * 4096) * 3072 + 1024 + h * 256;
        const u16* Qg = Y + ((long)b * 4096) * 3072 + h * 256;
#pragma unroll
        for (int i = 0; i < 8; i++) {
            R0.ak[i] = ldfrag(Kg, 3072, 16 * wq, i * 32, lane);
            R0.aq[i] = ldfrag(Qg, 3072, 16 * wq, i * 32, lane);
        }
    }

    // deferred-O carry state
    f32x4 oaccP[2];
#pragma unroll
    for (int j = 0; j < 2; j++) oaccP[j] = z4;
    bf16x8 amP0 = {}, amP1 = {};
    long obP = -1;

    auto body = [&](KQfrag& cur, KQfrag& nxt, int c) {
        const long bt0 = (long)b * 4096 + (long)c * 64;
        const int cn = (c < 63) ? c + 1 : 63;

        // ---- issue NEXT-chunk K/Q fragment prefetch ----
        {
            const long btn = (long)b * 4096 + (long)cn * 64;
            const u16* Kg = Y + btn * 3072 + 1024 + h * 256;
            const u16* Qg = Y + btn * 3072 + h * 256;
#pragma unroll
            for (int i = 0; i < 8; i++) {
                nxt.ak[i] = ldfrag(Kg, 3072, 16 * wq, i * 32, lane);
                nxt.aq[i] = ldfrag(Qg, 3072, 16 * wq, i * 32, lane);
            }
        }

        // ---- issue CURRENT-chunk V/T/M/sf loads ----
        const u16* Vr = Y + (bt0 + tW) * 3072 + 2048 + h * 256 + dvs * 64 + wh * 32;
        u16x4 v4[2];
#pragma unroll
        for (int j = 0; j < 2; j++) v4[j] = *(const u16x4*)(Vr + j * 16 + quad * 4);
        const u16* Tc = Tg + (size_t)(bh * 64 + c) * 4096;
        const u16* Mc = Mg + (size_t)(bh * 64 + c) * 4096;
        bf16x8 at0 = ldfrag(Tc, 64, 16 * wq, 0, lane);
        bf16x8 at1 = ldfrag(Tc, 64, 16 * wq, 32, lane);
        bf16x8 amN0 = ldfrag(Mc, 64, 16 * wq, 0, lane);
        bf16x8 amN1 = ldfrag(Mc, 64, 16 * wq, 32, lane);
        const float* sfc = sfg + (size_t)(bh * 64 + c) * 256;
        const float gam_l = sfc[tW];
        const float bg_l  = sfc[64 + tW];
        const float bet_l = sfc[128 + tW];
        const float ksc_l = sfc[192 + tW];
        const float gL    = sfc[63];

        // ---- deferred O of previous chunk: O = oaccP + M*U -> global ----
        if (obP >= 0) {
#pragma unroll
            for (int sj = 0; sj < 2; sj++) {
                bf16x8 ua0 = ldfrag(UTp, 72, wh * 32 + sj * 16, 0, lane);
                oaccP[sj] = __builtin_amdgcn_mfma_f32_16x16x32_bf16(ua0, amP0, oaccP[sj], 0, 0, 0);
                bf16x8 ua1 = ldfrag(UTp, 72, wh * 32 + sj * 16, 32, lane);
                oaccP[sj] = __builtin_amdgcn_mfma_f32_16x16x32_bf16(ua1, amP1, oaccP[sj], 0, 0, 0);
            }
#pragma unroll
            for (int sj = 0; sj < 2; sj++) {
                u16x4 o4;
#pragma unroll
                for (int r = 0; r < 4; r++) o4[r] = f2bf_h(oaccP[sj][r]);
                *(u16x4*)(Ob + obP + sj * 16 + quad * 4) = o4;
            }
        }
        amP0 = amN0; amP1 = amN1;

        // ---- P phase: pk/pq C = [dv-rows (wh half)][t-col (wq group)] ----
        f32x4 pk[2], pq[2];
#pragma unroll
        for (int j = 0; j < 2; j++) { pk[j] = z4; pq[j] = z4; }
#pragma unroll
        for (int i = 0; i < 8; i++) {
            bf16x8 sfr[2];
#pragma unroll
            for (int j = 0; j < 2; j++) sfr[j] = ldfrag(ST, 264, wh * 32 + j * 16, i * 32, lane);
#pragma unroll
            for (int j = 0; j < 2; j++) {
                pk[j] = __builtin_amdgcn_mfma_f32_16x16x32_bf16(sfr[j], cur.ak[i], pk[j], 0, 0, 0);
                pq[j] = __builtin_amdgcn_mfma_f32_16x16x32_bf16(sfr[j], cur.aq[i], pq[j], 0, 0, 0);
            }
        }

        // ---- KT build: raw K bits, rotated t; wh splits the dk range ----
#pragma unroll
        for (int i2 = 0; i2 < 4; i2++) {
            const int i = wh * 4 + i2;
            const u16* src = (const u16*)&cur.ak[i];
            u16* dst = KT + (i >> 1) * 4616 + ((i & 1) * 32 + quad * 8) * 72 + tph;
#pragma unroll
            for (int jj = 0; jj < 8; jj++) dst[jj * 72] = src[jj];
        }

        // ---- RHS = beta*V - beta*gam*pk ; oacc = gam*pq ----
        f32x4 oacc[2];
#pragma unroll
        for (int j = 0; j < 2; j++)
#pragma unroll
            for (int r = 0; r < 4; r++) {
                const int row = wh * 32 + j * 16 + quad * 4 + r;
                RHST[row * 72 + tW] = f2bf_h(bet_l * bf2f(v4[j][r]) - bg_l * pk[j][r]);
                oacc[j][r] = gam_l * pq[j][r];
            }
        block_barrier();   // B2 (RHST + KT visible)

        // ---- U: C[dv][t]; write UTp (plain) + UTk (ksc-folded) ----
        {
#pragma unroll
            for (int sj = 0; sj < 2; sj++) {
                f32x4 uu = z4;
                bf16x8 ra0 = ldfrag(RHST, 72, wh * 32 + sj * 16, 0, lane);
                uu = __builtin_amdgcn_mfma_f32_16x16x32_bf16(ra0, at0, uu, 0, 0, 0);
                bf16x8 ra1 = ldfrag(RHST, 72, wh * 32 + sj * 16, 32, lane);
                uu = __builtin_amdgcn_mfma_f32_16x16x32_bf16(ra1, at1, uu, 0, 0, 0);
#pragma unroll
                for (int r = 0; r < 4; r++) {
                    const int row = wh * 32 + sj * 16 + quad * 4 + r;
                    const float u = uu[r];
                    UTp[row * 72 + tW] = f2bf_h(u);
                    UTk[row * 72 + tW] = f2bf_h(ksc_l * u);
                }
            }
        }
        block_barrier();   // B3 (UTp/UTk visible)

        // ---- S update: S = gL*S + K^T (ksc.U) ; write ST ----
        {
#pragma unroll
            for (int i = 0; i < 2; i++)
#pragma unroll
                for (int j = 0; j < 4; j++) Sacc[i][j] *= gL;
            const u16* KTp = KT + wq * 4616;
#pragma unroll
            for (int k0 = 0; k0 < 64; k0 += 32) {
                bf16x8 au[2], bk[4];
#pragma unroll
                for (int i = 0; i < 2; i++) au[i] = ldfrag(UTk, 72, wh * 32 + i * 16, k0, lane);
#pragma unroll
                for (int j = 0; j < 4; j++)
                    bk[j] = *(const bf16x8*)(KTp + (size_t)(j * 16 + l15) * 72 +
                                             ((k0 + quad * 8 + toff[j]) & 63));
#pragma unroll
                for (int i = 0; i < 2; i++)
#pragma unroll
                    for (int j = 0; j < 4; j++)
                        Sacc[i][j] = __builtin_amdgcn_mfma_f32_16x16x32_bf16(au[i], bk[j], Sacc[i][j], 0, 0, 0);
            }
#pragma unroll
            for (int i = 0; i < 2; i++)
#pragma unroll
                for (int j = 0; j < 4; j++)
#pragma unroll
                    for (int r = 0; r < 4; r++)
                        ST[(wh * 32 + i * 16 + quad * 4 + r) * 264 + wq * 64 + j * 16 + l15] = f2bf_h(Sacc[i][j][r]);
        }
        block_barrier();   // B4 (ST visible for next chunk)

        // ---- save deferred-O state ----
#pragma unroll
        for (int j = 0; j < 2; j++) oaccP[j] = oacc[j];
        obP = (bt0 + tW) * 1024 + h * 256 + (long)dvs * 64 + wh * 32;
    };

#pragma unroll 1
    for (int c = 0; c < 64; c += 2) {
        body(R0, R1, c);
        body(R1, R0, c + 1);
    }

    // ---- final deferred O (chunk 63) ----
    {
#pragma unroll
        for (int sj = 0; sj < 2; sj++) {
            bf16x8 ua0 = ldfrag(UTp, 72, wh * 32 + sj * 16, 0, lane);
            oaccP[sj] = __builtin_amdgcn_mfma_f32_16x16x32_bf16(ua0, amP0, oaccP[sj], 0, 0, 0);
            bf16x8 ua1 = ldfrag(UTp, 72, wh * 32 + sj * 16, 32, lane);
            oaccP[sj] = __builtin_amdgcn_mfma_f32_16x16x32_bf16(ua1, amP1, oaccP[sj], 0, 0, 0);
        }
#pragma unroll
        for (int sj = 0; sj < 2; sj++) {
            u16x4 o4;
#pragma unroll
            for (int r = 0; r < 4; r++) o4[r] = f2bf_h(oaccP[sj][r]);
            *(u16x4*)(Ob + obP + sj * 16 + quad * 4) = o4;
        }
    }
}

// ---------------------------------------------------------------------------
// Gated RMSNorm + SiLU; writes og IN PLACE into G.
// ---------------------------------------------------------------------------
__global__ __launch_bounds__(256) void gate_norm_kernel(const u16* __restrict__ O,
                                                        u16* __restrict__ G,
                                                        const float* __restrict__ norm_w) {
    const long row = blockIdx.x >> 2;
    const int h = blockIdx.x & 3;
    const int dv = threadIdx.x;
    const long idx = row * 1024 + h * 256 + dv;
    float o = bf2f(O[idx]);
    float s = o * o;
#pragma unroll
    for (int off = 32; off; off >>= 1) s += __shfl_xor(s, off, 64);
    __shared__ float wsum[4];
    if ((dv & 63) == 0) wsum[dv >> 6] = s;
    __syncthreads();
    const float tot = wsum[0] + wsum[1] + wsum[2] + wsum[3];
    const float r = rsqrtf(tot * (1.f / 256.f) + 1e-5f);
    const float g = bf2f(G[idx]);
    const float val = o * r * norm_w[dv] * (g / (1.f + expf(-g)));
    G[idx] = f2bf(val);
}

// ---------------------------------------------------------------------------
extern "C" void kernel_launch(void* const* d_in, const int* in_sizes, int n_in,
                              void* d_out, int out_size, void* d_ws, size_t ws_size,
                              hipStream_t stream) {
    const float* x       = (const float*)d_in[0];
    const float* Wq      = (const float*)d_in[1];
    const float* Wk      = (const float*)d_in[2];
    const float* Wv      = (const float*)d_in[3];
    const float* Wb      = (const float*)d_in[4];
    const float* Wa      = (const float*)d_in[5];
    const float* A_log   = (const float*)d_in[6];
    const float* dt_bias = (const float*)d_in[7];
    const float* Wg      = (const float*)d_in[8];
    const float* norm_w  = (const float*)d_in[9];
    const float* Wo      = (const float*)d_in[10];

    // workspace: identical 171 MB footprint as previous rounds (proven to fit).
    char* p = (char*)d_ws;
    u16*   WT   = (u16*)p;   p += (size_t)5120 * 1024 * 2;   // WqT|WkT|WvT|WgT|WoT bf16
    u16*   Y    = (u16*)p;   p += (size_t)16384 * 3072 * 2;  // q|k|v bf16
    u16*   G    = (u16*)p;   p += (size_t)16384 * 1024 * 2;  // T|M (prep+scan), then gate/og
    u16*   XO   = (u16*)p;   p += (size_t)16384 * 1024 * 2;  // xb (early), O (scan output)
    float* beta = (float*)p; p += (size_t)16384 * 4 * 4;
    float* dec  = (float*)p; p += (size_t)16384 * 4 * 4;

    u16* Tg = G;                                  // [16*64][64*64] bf16, 8.4 MB
    u16* Mg = G + (size_t)1024 * 4096;            // same, next 8.4 MB
    // sfg (1 MB) overlays WqT, which is dead after the big QKV GEMM.
    float* sfg = (float*)WT;                      // [16*64][256] f32

    cvt_kernel<<<16384, 256, 0, stream>>>(x, XO);

    dim3 tb(32, 8), tg(32, 32);
    transpose_kernel<<<tg, tb, 0, stream>>>(Wq, WT + (size_t)0 * 1024 * 1024);
    transpose_kernel<<<tg, tb, 0, stream>>>(Wk, WT + (size_t)1 * 1024 * 1024);
    transpose_kernel<<<tg, tb, 0, stream>>>(Wv, WT + (size_t)2 * 1024 * 1024);
    transpose_kernel<<<tg, tb, 0, stream>>>(Wg, WT + (size_t)3 * 1024 * 1024);
    transpose_kernel<<<tg, tb, 0, stream>>>(Wo, WT + (size_t)4 * 1024 * 1024);

    // Y = xb @ [Wq|Wk|Wv]   (M=16384, N=3072, K=1024)
    gemm_kernel<0><<<dim3(3072 / 128, 16384 / 128), 256, 0, stream>>>(
        XO, WT, (void*)Y, 16384, 3072, 1024, 3072);

    norm_beta_kernel<<<16384, 1024, 0, stream>>>(XO, Y, Wb, Wa, A_log, dt_bias, beta, dec);

    // prep also writes sfg into the dead WqT region
    prep_kernel<<<1024, 256, 0, stream>>>(Y, beta, dec, Tg, Mg, sfg);

    // xb dead; scan writes O into XO
    scan_kernel<<<64, 512, 0, stream>>>(Y, sfg, Tg, Mg, XO);

    // gate = x @ Wg (fp32 A read directly; overwrites T/M region -> after scan)
    gemm_a32_kernel<<<dim3(1024 / 128, 16384 / 128), 256, 0, stream>>>(
        x, WT + (size_t)3072 * 1024, G, 16384, 1024, 1024, 1024);

    gate_norm_kernel<<<16384 * 4, 256, 0, stream>>>(XO, G, norm_w);

    // out = og @ Wo   (fp32 out)
    gemm_kernel<1><<<dim3(1024 / 128, 16384 / 128), 256, 0, stream>>>(
        G, WT + (size_t)4096 * 1024, d_out, 16384, 1024, 1024, 1024);
}

// Round 4
// 1007.975 us; speedup vs baseline: 1.4097x; 1.4097x over previous
//
#include <hip/hip_runtime.h>

typedef unsigned short u16;
typedef __bf16 bf16x8 __attribute__((ext_vector_type(8)));
typedef u16 u16x8 __attribute__((ext_vector_type(8)));
typedef u16 u16x4 __attribute__((ext_vector_type(4)));
typedef float f32x4 __attribute__((ext_vector_type(4)));

__device__ __forceinline__ float bf2f(u16 v) {
    union { unsigned u; float f; } c; c.u = ((unsigned)v) << 16; return c.f;
}
__device__ __forceinline__ u16 f2bf(float f) {
    union { float f; unsigned u; } c; c.f = f;
    unsigned u = c.u;
    unsigned r = (u + 0x7fffu + ((u >> 16) & 1u)) >> 16;
    return (u16)r;
}
// HW RNE f32->bf16 (single v_cvt, same rounding as f2bf; scan hot paths only)
__device__ __forceinline__ u16 f2bf_h(float f) {
    __bf16 h = (__bf16)f;
    union { __bf16 h; u16 u; } c; c.h = h; return c.u;
}

// MFMA fragment load (works for LDS or global pointers): LEFT operand from
// [m][k] row-major, or RIGHT operand from [n][k] row-major.
// row = row0 + (lane&15), k = k0 + (lane>>4)*8 .. +8.
__device__ __forceinline__ bf16x8 ldfrag(const u16* base, int stride, int row0, int k0, int lane) {
    return *(const bf16x8*)(base + (size_t)(row0 + (lane & 15)) * stride + k0 + (lane >> 4) * 8);
}

// Raw workgroup barrier: commits LDS (lgkmcnt only) but does NOT drain vmcnt,
// so cross-chunk global prefetches stay in flight (counted-vmcnt pattern).
__device__ __forceinline__ void block_barrier() {
    __builtin_amdgcn_sched_barrier(0);
    asm volatile("s_waitcnt lgkmcnt(0)");
    __builtin_amdgcn_s_barrier();
    __builtin_amdgcn_sched_barrier(0);
}

// ---------------------------------------------------------------------------
// fp32 -> bf16 elementwise convert
// ---------------------------------------------------------------------------
__global__ __launch_bounds__(256) void cvt_kernel(const float* __restrict__ src,
                                                  u16* __restrict__ dst) {
    const long i = ((long)blockIdx.x * 256 + threadIdx.x) * 4;
    f32x4 v = *(const f32x4*)(src + i);
    u16x4 o;
#pragma unroll
    for (int r = 0; r < 4; r++) o[r] = f2bf(v[r]);
    *(u16x4*)(dst + i) = o;
}

// ---------------------------------------------------------------------------
// Weight transpose + cvt: src fp32 [1024,1024] (k,n) -> dst bf16 (n,k)
// ---------------------------------------------------------------------------
__global__ __launch_bounds__(256) void transpose_kernel(const float* __restrict__ src,
                                                        u16* __restrict__ dst) {
    __shared__ float tile[32][33];
    const int n0 = blockIdx.x * 32, k0 = blockIdx.y * 32;
    const int tx = threadIdx.x, ty = threadIdx.y;   // 32 x 8
#pragma unroll
    for (int i = 0; i < 32; i += 8)
        tile[ty + i][tx] = src[(long)(k0 + ty + i) * 1024 + n0 + tx];
    __syncthreads();
#pragma unroll
    for (int i = 0; i < 32; i += 8)
        dst[(long)(n0 + ty + i) * 1024 + k0 + tx] = f2bf(tile[tx][ty + i]);
}

// ---------------------------------------------------------------------------
// MFMA GEMM: C[M,N] = A[M,K](bf16) * BT[N,K](bf16)^T, fp32 accum.
// ---------------------------------------------------------------------------
#define LDK 40

template <int F32OUT>
__global__ __launch_bounds__(256) void gemm_kernel(const u16* __restrict__ A,
                                                   const u16* __restrict__ BT,
                                                   void* __restrict__ Cv,
                                                   int M, int N, int K, int ldc) {
    __shared__ u16 As[128][LDK];
    __shared__ u16 Bs[128][LDK];
    const int tid  = threadIdx.x;
    const int lane = tid & 63;
    const int wave = tid >> 6;
    const int wm   = (wave >> 1) * 64;
    const int wn   = (wave & 1) * 64;
    const long m0  = (long)blockIdx.y * 128;
    const long n0  = (long)blockIdx.x * 128;

    const f32x4 zero = {0.f, 0.f, 0.f, 0.f};
    f32x4 acc[4][4];
#pragma unroll
    for (int i = 0; i < 4; i++)
#pragma unroll
        for (int j = 0; j < 4; j++) acc[i][j] = zero;

    const int r0 = tid >> 2;
    const int c0 = (tid & 3) * 8;
    const u16* Ag = A + (m0 + r0) * K + c0;
    const u16* Bg = BT + (n0 + r0) * K + c0;

    for (int k0 = 0; k0 < K; k0 += 32) {
        u16x8 a0 = *(const u16x8*)(Ag + k0);
        u16x8 a1 = *(const u16x8*)(Ag + (long)64 * K + k0);
        u16x8 b0 = *(const u16x8*)(Bg + k0);
        u16x8 b1 = *(const u16x8*)(Bg + (long)64 * K + k0);
        *(u16x8*)(&As[r0][c0])      = a0;
        *(u16x8*)(&As[r0 + 64][c0]) = a1;
        *(u16x8*)(&Bs[r0][c0])      = b0;
        *(u16x8*)(&Bs[r0 + 64][c0]) = b1;
        __syncthreads();
        const int qk = (lane >> 4) * 8;
        const int mr = lane & 15;
        bf16x8 af[4], bfr[4];
#pragma unroll
        for (int i = 0; i < 4; i++) af[i]  = *(const bf16x8*)(&As[wm + i * 16 + mr][qk]);
#pragma unroll
        for (int j = 0; j < 4; j++) bfr[j] = *(const bf16x8*)(&Bs[wn + j * 16 + mr][qk]);
#pragma unroll
        for (int i = 0; i < 4; i++)
#pragma unroll
            for (int j = 0; j < 4; j++)
                acc[i][j] = __builtin_amdgcn_mfma_f32_16x16x32_bf16(af[i], bfr[j], acc[i][j], 0, 0, 0);
        __syncthreads();
    }

    const int cr = (lane >> 4) * 4;
    const int cc = lane & 15;
#pragma unroll
    for (int i = 0; i < 4; i++) {
#pragma unroll
        for (int j = 0; j < 4; j++) {
            const long m = m0 + wm + i * 16 + cr;
            const long n = n0 + wn + j * 16 + cc;
            if (F32OUT) {
                float* C = (float*)Cv;
#pragma unroll
                for (int r = 0; r < 4; r++) C[(m + r) * ldc + n] = acc[i][j][r];
            } else {
                u16* C = (u16*)Cv;
#pragma unroll
                for (int r = 0; r < 4; r++) C[(m + r) * ldc + n] = f2bf(acc[i][j][r]);
            }
        }
    }
}

// ---------------------------------------------------------------------------
// Same GEMM but A operand is fp32 in global (converted to bf16 at staging).
// ---------------------------------------------------------------------------
__global__ __launch_bounds__(256) void gemm_a32_kernel(const float* __restrict__ A,
                                                       const u16* __restrict__ BT,
                                                       u16* __restrict__ C,
                                                       int M, int N, int K, int ldc) {
    __shared__ u16 As[128][LDK];
    __shared__ u16 Bs[128][LDK];
    const int tid  = threadIdx.x;
    const int lane = tid & 63;
    const int wave = tid >> 6;
    const int wm   = (wave >> 1) * 64;
    const int wn   = (wave & 1) * 64;
    const long m0  = (long)blockIdx.y * 128;
    const long n0  = (long)blockIdx.x * 128;

    const f32x4 zero = {0.f, 0.f, 0.f, 0.f};
    f32x4 acc[4][4];
#pragma unroll
    for (int i = 0; i < 4; i++)
#pragma unroll
        for (int j = 0; j < 4; j++) acc[i][j] = zero;

    const int r0 = tid >> 2;
    const int c0 = (tid & 3) * 8;
    const float* Ag = A + (m0 + r0) * K + c0;
    const u16* Bg = BT + (n0 + r0) * K + c0;

    for (int k0 = 0; k0 < K; k0 += 32) {
        f32x4 af0 = *(const f32x4*)(Ag + k0);
        f32x4 af1 = *(const f32x4*)(Ag + k0 + 4);
        f32x4 ag0 = *(const f32x4*)(Ag + (long)64 * K + k0);
        f32x4 ag1 = *(const f32x4*)(Ag + (long)64 * K + k0 + 4);
        u16x8 b0 = *(const u16x8*)(Bg + k0);
        u16x8 b1 = *(const u16x8*)(Bg + (long)64 * K + k0);
        u16x8 a0, a1;
#pragma unroll
        for (int r = 0; r < 4; r++) {
            a0[r] = f2bf(af0[r]); a0[r + 4] = f2bf(af1[r]);
            a1[r] = f2bf(ag0[r]); a1[r + 4] = f2bf(ag1[r]);
        }
        *(u16x8*)(&As[r0][c0])      = a0;
        *(u16x8*)(&As[r0 + 64][c0]) = a1;
        *(u16x8*)(&Bs[r0][c0])      = b0;
        *(u16x8*)(&Bs[r0 + 64][c0]) = b1;
        __syncthreads();
        const int qk = (lane >> 4) * 8;
        const int mr = lane & 15;
        bf16x8 af[4], bfr[4];
#pragma unroll
        for (int i = 0; i < 4; i++) af[i]  = *(const bf16x8*)(&As[wm + i * 16 + mr][qk]);
#pragma unroll
        for (int j = 0; j < 4; j++) bfr[j] = *(const bf16x8*)(&Bs[wn + j * 16 + mr][qk]);
#pragma unroll
        for (int i = 0; i < 4; i++)
#pragma unroll
            for (int j = 0; j < 4; j++)
                acc[i][j] = __builtin_amdgcn_mfma_f32_16x16x32_bf16(af[i], bfr[j], acc[i][j], 0, 0, 0);
        __syncthreads();
    }

    const int cr = (lane >> 4) * 4;
    const int cc = lane & 15;
#pragma unroll
    for (int i = 0; i < 4; i++) {
#pragma unroll
        for (int j = 0; j < 4; j++) {
            const long m = m0 + wm + i * 16 + cr;
            const long n = n0 + wn + j * 16 + cc;
#pragma unroll
            for (int r = 0; r < 4; r++) C[(m + r) * ldc + n] = f2bf(acc[i][j][r]);
        }
    }
}

// ---------------------------------------------------------------------------
// Fused: in-place L2-normalize q (x 1/16) and k per head; beta & dec per head.
// ---------------------------------------------------------------------------
__global__ __launch_bounds__(1024) void norm_beta_kernel(
    const u16* __restrict__ xb, u16* __restrict__ Y,
    const float* __restrict__ Wb, const float* __restrict__ Wa,
    const float* __restrict__ A_log, const float* __restrict__ dt_bias,
    float* __restrict__ beta, float* __restrict__ dec) {
    const long row = blockIdx.x;
    const int c = threadIdx.x;
    const int h = c >> 8;
    float qv = bf2f(Y[row * 3072 + c]);
    float kv = bf2f(Y[row * 3072 + 1024 + c]);
    float xv = bf2f(xb[row * 1024 + c]);
    float vals[10];
    vals[0] = qv * qv;
    vals[1] = kv * kv;
#pragma unroll
    for (int hh = 0; hh < 4; hh++) vals[2 + hh] = xv * Wb[c * 4 + hh];
#pragma unroll
    for (int hh = 0; hh < 4; hh++) vals[6 + hh] = xv * Wa[c * 4 + hh];
#pragma unroll
    for (int i = 0; i < 10; i++)
        for (int off = 32; off; off >>= 1) vals[i] += __shfl_xor(vals[i], off, 64);

    __shared__ float wred[16][10];
    __shared__ float sQ[4], sK[4];
    const int w = c >> 6;
    if ((c & 63) == 0) {
#pragma unroll
        for (int i = 0; i < 10; i++) wred[w][i] = vals[i];
    }
    __syncthreads();
    if (c < 4) {
        float s = wred[c * 4 + 0][0] + wred[c * 4 + 1][0] + wred[c * 4 + 2][0] + wred[c * 4 + 3][0];
        sQ[c] = rsqrtf(s + 1e-6f) * 0.0625f;
    } else if (c < 8) {
        int hh = c - 4;
        float s = wred[hh * 4 + 0][1] + wred[hh * 4 + 1][1] + wred[hh * 4 + 2][1] + wred[hh * 4 + 3][1];
        sK[hh] = rsqrtf(s + 1e-6f);
    } else if (c < 12) {
        int hh = c - 8;
        float s = 0.f;
        for (int ww = 0; ww < 16; ww++) s += wred[ww][2 + hh];
        beta[row * 4 + hh] = 1.f / (1.f + expf(-s));
    } else if (c < 16) {
        int hh = c - 12;
        float s = 0.f;
        for (int ww = 0; ww < 16; ww++) s += wred[ww][6 + hh];
        float z = s + dt_bias[hh];
        float sp = (z > 0.f) ? (z + log1pf(expf(-z))) : log1pf(expf(z));
        dec[row * 4 + hh] = expf(-expf(A_log[hh]) * sp);
    }
    __syncthreads();
    Y[row * 3072 + c]        = f2bf(qv * sQ[h]);
    Y[row * 3072 + 1024 + c] = f2bf(kv * sK[h]);
}

// ---------------------------------------------------------------------------
// PASS A (chunk-parallel prep): per (bh, chunk) compute A matrix, T=(I+A)^-1
// via nilpotent doubling, and M matrix. Writes T, M (bf16 [64][64]) to global.
// Also writes the per-chunk scalar tables sfg[bh*64+c][256]:
//   [0:64)=gam  [64:128)=beta*gam  [128:192)=beta  [192:256)=ksc (gamL/gam)
// ---------------------------------------------------------------------------
__global__ __launch_bounds__(256) void prep_kernel(const u16* __restrict__ Y,
                                                   const float* __restrict__ beta,
                                                   const float* __restrict__ dec,
                                                   u16* __restrict__ Tg,
                                                   u16* __restrict__ Mg,
                                                   float* __restrict__ sfg) {
    __shared__ __attribute__((aligned(16))) u16 lds[38400];
    __shared__ float sf[320];
    u16* KS  = lds;            // 64 x 264
    u16* QS  = lds + 16896;    // 64 x 264
    u16* AM  = lds + 33792;    // 64 x 72
    // overlays (valid after G phase; KS/QS dead):
    u16* Tm  = lds;            // 64 x 72
    u16* AMT = lds + 4608;
    u16* MP  = lds + 9216;
    u16* MPT = lds + 13824;

    const int bx = blockIdx.x;
    const int bh = bx >> 6, c = bx & 63;
    const int b = bh >> 2, h = bh & 3;
    const int tid = threadIdx.x, lane = tid & 63, wv = tid >> 6;
    const int quad = lane >> 4, l15 = lane & 15;
    const int tld = tid >> 2, seg = tid & 3;
    const long bt0 = (long)b * 4096 + c * 64;
    u16* Tc = Tg + (size_t)(bh * 64 + c) * 4096;
    u16* Mc = Mg + (size_t)(bh * 64 + c) * 4096;
    const f32x4 z4 = {0.f, 0.f, 0.f, 0.f};

    // ---- stage K,Q; gamma prefix ----
    {
        const long rb = (bt0 + tld) * 3072 + h * 256 + seg * 64;
#pragma unroll
        for (int i = 0; i < 8; i++) {
            *(u16x8*)&KS[tld * 264 + seg * 64 + i * 8] = *(const u16x8*)&Y[rb + 1024 + i * 8];
            *(u16x8*)&QS[tld * 264 + seg * 64 + i * 8] = *(const u16x8*)&Y[rb + i * 8];
        }
    }
    if (wv == 0) {
        float d   = dec [(bt0 + lane) * 4 + h];
        float bt_ = beta[(bt0 + lane) * 4 + h];
        float lg = log2f(fmaxf(d, 1e-30f));
#pragma unroll
        for (int off = 1; off < 64; off <<= 1) {
            float o = __shfl_up(lg, off, 64);
            if (lane >= off) lg += o;
        }
        sf[lane] = lg; sf[192 + lane] = bt_;
        float lgL = __shfl(lg, 63, 64);
        float g = exp2f(lg);
        float* sfc = sfg + (size_t)(bh * 64 + c) * 256;
        sfc[lane]       = g;
        sfc[64 + lane]  = bt_ * g;
        sfc[128 + lane] = bt_;
        sfc[192 + lane] = exp2f(lgL - lg);
    }
    __syncthreads();   // B1

    // ---- G phase: waves 0-1 -> A matrix (LDS); waves 2-3 -> M (global) ----
    {
        const u16* Ab = (wv < 2) ? KS : QS;
        const int mb = (wv & 1) * 32;
        f32x4 g[2][4];
#pragma unroll
        for (int mi = 0; mi < 2; mi++)
#pragma unroll
            for (int sj = 0; sj < 4; sj++) g[mi][sj] = z4;
#pragma unroll 2
        for (int k0 = 0; k0 < 256; k0 += 32) {
            bf16x8 bfr[4];
#pragma unroll
            for (int sj = 0; sj < 4; sj++) bfr[sj] = ldfrag(KS, 264, sj * 16, k0, lane);
#pragma unroll
            for (int mi = 0; mi < 2; mi++) {
                bf16x8 af = ldfrag(Ab, 264, mb + mi * 16, k0, lane);
#pragma unroll
                for (int sj = 0; sj < 4; sj++)
                    g[mi][sj] = __builtin_amdgcn_mfma_f32_16x16x32_bf16(af, bfr[sj], g[mi][sj], 0, 0, 0);
            }
        }
#pragma unroll
        for (int mi = 0; mi < 2; mi++)
#pragma unroll
            for (int sj = 0; sj < 4; sj++)
#pragma unroll
                for (int r = 0; r < 4; r++) {
                    const int t_ = mb + mi * 16 + quad * 4 + r, s_ = sj * 16 + l15;
                    if (wv < 2)
                        AM[t_ * 72 + s_] = (s_ < t_) ? f2bf(sf[192 + t_] * exp2f(sf[t_] - sf[s_]) * g[mi][sj][r]) : (u16)0;
                    else
                        Mc[t_ * 64 + s_] = (s_ <= t_) ? f2bf(exp2f(sf[t_] - sf[s_]) * g[mi][sj][r]) : (u16)0;
                }
    }
    __syncthreads();   // B2 (KS/QS dead)

    // ---- solve init: T = I - A, A^T ----
    {
        const int t_ = tid >> 2;
#pragma unroll
        for (int i = 0; i < 16; i++) {
            const int s_ = (tid & 3) * 16 + i;
            const u16 a = AM[t_ * 72 + s_];
            Tm[t_ * 72 + s_] = (t_ == s_) ? (u16)0x3F80 : (u16)(a ^ 0x8000);
            AMT[s_ * 72 + t_] = a;
        }
    }
    __syncthreads();   // B3

    // ---- r1: Mp = N*N ----
    {
        f32x4 sq[4];
#pragma unroll
        for (int sj = 0; sj < 4; sj++) sq[sj] = z4;
#pragma unroll
        for (int k0 = 0; k0 < 64; k0 += 32) {
            bf16x8 a = ldfrag(AM, 72, 16 * wv, k0, lane);
#pragma unroll
            for (int sj = 0; sj < 4; sj++) {
                bf16x8 bb = ldfrag(AMT, 72, sj * 16, k0, lane);
                sq[sj] = __builtin_amdgcn_mfma_f32_16x16x32_bf16(a, bb, sq[sj], 0, 0, 0);
            }
        }
#pragma unroll
        for (int sj = 0; sj < 4; sj++)
#pragma unroll
            for (int r = 0; r < 4; r++) {
                const int t_ = 16 * wv + quad * 4 + r, s_ = sj * 16 + l15;
                const u16 vbf = f2bf(sq[sj][r]);
                MP[t_ * 72 + s_] = vbf;
                MPT[s_ * 72 + t_] = vbf;
            }
        __syncthreads();   // B4
    }

    // ---- fused rounds: T += T*Mp ; Mp <- Mp*Mp (skip on last) ----
#pragma unroll 1
    for (int jj = 0; jj < 5; jj++) {
        const bool last = (jj == 4);
        f32x4 pp[4], sq[4];
#pragma unroll
        for (int sj = 0; sj < 4; sj++) {
            sq[sj] = z4;
#pragma unroll
            for (int r = 0; r < 4; r++)
                pp[sj][r] = bf2f(Tm[(16 * wv + quad * 4 + r) * 72 + sj * 16 + l15]);
        }
#pragma unroll
        for (int k0 = 0; k0 < 64; k0 += 32) {
            bf16x8 at = ldfrag(Tm, 72, 16 * wv, k0, lane);
            bf16x8 am = ldfrag(MP, 72, 16 * wv, k0, lane);
#pragma unroll
            for (int sj = 0; sj < 4; sj++) {
                bf16x8 bb = ldfrag(MPT, 72, sj * 16, k0, lane);
                pp[sj] = __builtin_amdgcn_mfma_f32_16x16x32_bf16(at, bb, pp[sj], 0, 0, 0);
                if (!last) sq[sj] = __builtin_amdgcn_mfma_f32_16x16x32_bf16(am, bb, sq[sj], 0, 0, 0);
            }
        }
        __syncthreads();
#pragma unroll
        for (int sj = 0; sj < 4; sj++)
#pragma unroll
            for (int r = 0; r < 4; r++) {
                const int t_ = 16 * wv + quad * 4 + r, s_ = sj * 16 + l15;
                Tm[t_ * 72 + s_] = f2bf(pp[sj][r]);
                if (!last) {
                    const u16 vbf = f2bf(sq[sj][r]);
                    MP[t_ * 72 + s_] = vbf;
                    MPT[s_ * 72 + t_] = vbf;
                }
            }
        __syncthreads();
    }

    // ---- write T to global ----
    {
        const int t_ = tid >> 2;
#pragma unroll
        for (int i = 0; i < 16; i++) {
            const int s_ = (tid & 3) * 16 + i;
            Tc[t_ * 64 + s_] = Tm[t_ * 72 + s_];
        }
    }
}

// ---------------------------------------------------------------------------
// PASS B (sequential scan): grid 64 = bh(16) x dvs(4), 512 threads / 8 waves,
// ROLE-SPLIT: waves 0-3 = K-role (wq = wv&3), waves 4-7 = Q-role.
//  - each wave double-buffers ONLY its role's fragments (64 VGPR, not 128)
//  - K-role: pk, KT build, RHS.  Q-role: pq, deferred-O, oacc.
//  - U phase split by dv-halves across roles; S phase dv-half per role.
//  - __launch_bounds__(512,2): 2 waves/SIMD, 256-VGPR cap (R3's (512,1) made
//    the allocator target 128 VGPR -> 552 MB scratch spill; this fixes it).
// 3 barriers/chunk. LDS 96 KB -> 1 block/CU.
// ---------------------------------------------------------------------------
struct Frag { bf16x8 f[8]; };

__global__ __launch_bounds__(512, 2) void scan_kernel(const u16* __restrict__ Y,
                                                      const float* __restrict__ sfg,
                                                      const u16* __restrict__ Tg,
                                                      const u16* __restrict__ Mg,
                                                      u16* __restrict__ Ob) {
    __shared__ __attribute__((aligned(16))) u16 KT[4 * 4616];   // [dk-panel][dk6*72 + t_rot]
    __shared__ __attribute__((aligned(16))) u16 ST[64 * 264];   // [dv][dk]
    __shared__ __attribute__((aligned(16))) u16 RHST[64 * 72];  // [dv][t]
    __shared__ __attribute__((aligned(16))) u16 UTp[64 * 72];   // [dv][t] plain
    __shared__ __attribute__((aligned(16))) u16 UTk[64 * 72];   // [dv][t] ksc-folded

    const int bx = blockIdx.x;
    const int bh = bx >> 2, dvs = bx & 3;
    const int b = bh >> 2, h = bh & 3;
    const int tid = threadIdx.x, lane = tid & 63, wv = tid >> 6;
    const int wq = wv & 3;           // t-group (16 t rows)
    const int isQ = wv >> 2;         // role: 0 = K-side, 1 = Q-side
    const int quad = lane >> 4, l15 = lane & 15;
    const int tW = 16 * wq + l15;                     // lane's t (output col)
    const int tph = 16 * ((wq + quad) & 3) + l15;     // rotated t for KT writes
    int toff[4];                                      // KT read t-rotation per dk-tile
#pragma unroll
    for (int j = 0; j < 4; j++) toff[j] = ((((j << 1) + (l15 >> 3)) & 3) << 4);
    const f32x4 z4 = {0.f, 0.f, 0.f, 0.f};

    f32x4 Sacc[2][4];   // [dv-tile within role half][dk-tile within wq slice]
#pragma unroll
    for (int i = 0; i < 2; i++)
#pragma unroll
        for (int j = 0; j < 4; j++) Sacc[i][j] = z4;
    for (int i = tid; i < 64 * 264; i += 512) ST[i] = 0;
    __syncthreads();

    const long roleOff = isQ ? 0 : 1024;   // q at +0, k at +1024 in Y rows
    Frag F0, F1;
    {
        const u16* Pg = Y + ((long)b * 4096) * 3072 + roleOff + h * 256;
#pragma unroll
        for (int i = 0; i < 8; i++) F0.f[i] = ldfrag(Pg, 3072, 16 * wq, i * 32, lane);
    }

    // deferred-O carry state (Q-role only)
    f32x4 oaccP[4];
#pragma unroll
    for (int j = 0; j < 4; j++) oaccP[j] = z4;
    bf16x8 amP0 = {}, amP1 = {};
    long obP = 0;
    int havePrev = 0;

    auto body = [&](Frag& cur, Frag& nxt, int c) {
        const long bt0 = (long)b * 4096 + (long)c * 64;
        const int cn = (c < 63) ? c + 1 : 63;

        // ---- issue NEXT-chunk fragment prefetch (role's operand only) ----
        {
            const u16* Pg = Y + ((long)b * 4096 + (long)cn * 64) * 3072 + roleOff + h * 256;
#pragma unroll
            for (int i = 0; i < 8; i++) nxt.f[i] = ldfrag(Pg, 3072, 16 * wq, i * 32, lane);
        }

        // ---- current-chunk T + scalars (both roles) ----
        const u16* Tc = Tg + (size_t)(bh * 64 + c) * 4096;
        bf16x8 at0 = ldfrag(Tc, 64, 16 * wq, 0, lane);
        bf16x8 at1 = ldfrag(Tc, 64, 16 * wq, 32, lane);
        const float* sfc = sfg + (size_t)(bh * 64 + c) * 256;
        const float gam_l = sfc[tW];
        const float bg_l  = sfc[64 + tW];
        const float bet_l = sfc[128 + tW];
        const float ksc_l = sfc[192 + tW];
        const float gL    = sfc[63];

        u16x4 v4[4];
        if (!isQ) {
            // K-role: V loads (for RHS)
            const u16* Vr = Y + (bt0 + tW) * 3072 + 2048 + h * 256 + dvs * 64;
#pragma unroll
            for (int j = 0; j < 4; j++) v4[j] = *(const u16x4*)(Vr + j * 16 + quad * 4);
        } else {
            // Q-role: M loads + deferred O of previous chunk
            const u16* Mc = Mg + (size_t)(bh * 64 + c) * 4096;
            bf16x8 amN0 = ldfrag(Mc, 64, 16 * wq, 0, lane);
            bf16x8 amN1 = ldfrag(Mc, 64, 16 * wq, 32, lane);
            if (havePrev) {
#pragma unroll
                for (int sj = 0; sj < 4; sj++) {
                    bf16x8 ua0 = ldfrag(UTp, 72, sj * 16, 0, lane);
                    oaccP[sj] = __builtin_amdgcn_mfma_f32_16x16x32_bf16(ua0, amP0, oaccP[sj], 0, 0, 0);
                    bf16x8 ua1 = ldfrag(UTp, 72, sj * 16, 32, lane);
                    oaccP[sj] = __builtin_amdgcn_mfma_f32_16x16x32_bf16(ua1, amP1, oaccP[sj], 0, 0, 0);
                }
#pragma unroll
                for (int sj = 0; sj < 4; sj++) {
                    u16x4 o4;
#pragma unroll
                    for (int r = 0; r < 4; r++) o4[r] = f2bf_h(oaccP[sj][r]);
                    *(u16x4*)(Ob + obP + sj * 16 + quad * 4) = o4;
                }
            }
            amP0 = amN0; amP1 = amN1;
        }

        // ---- P phase: p = ST @ role-frag, C[dv-tile][t=wq group] ----
        f32x4 p[4];
#pragma unroll
        for (int j = 0; j < 4; j++) p[j] = z4;
#pragma unroll
        for (int i = 0; i < 8; i++) {
            bf16x8 sfr[4];
#pragma unroll
            for (int j = 0; j < 4; j++) sfr[j] = ldfrag(ST, 264, j * 16, i * 32, lane);
#pragma unroll
            for (int j = 0; j < 4; j++)
                p[j] = __builtin_amdgcn_mfma_f32_16x16x32_bf16(sfr[j], cur.f[i], p[j], 0, 0, 0);
        }

        if (!isQ) {
            // ---- KT build from cur (K frags): raw bits, rotated t ----
#pragma unroll
            for (int i = 0; i < 8; i++) {
                const u16* src = (const u16*)&cur.f[i];
                u16* dst = KT + (i >> 1) * 4616 + ((i & 1) * 32 + quad * 8) * 72 + tph;
#pragma unroll
                for (int jj = 0; jj < 8; jj++) dst[jj * 72] = src[jj];
            }
            // ---- RHS = beta*V - beta*gam*pk ----
#pragma unroll
            for (int j = 0; j < 4; j++)
#pragma unroll
                for (int r = 0; r < 4; r++) {
                    const int row = j * 16 + quad * 4 + r;
                    RHST[row * 72 + tW] = f2bf_h(bet_l * bf2f(v4[j][r]) - bg_l * p[j][r]);
                }
        } else {
            // ---- oacc = gam*pq (becomes next chunk's deferred-O base) ----
#pragma unroll
            for (int j = 0; j < 4; j++)
#pragma unroll
                for (int r = 0; r < 4; r++) oaccP[j][r] = gam_l * p[j][r];
            obP = (bt0 + tW) * 1024 + h * 256 + (long)dvs * 64;
            havePrev = 1;
        }
        block_barrier();   // B2 (RHST + KT visible)

        // ---- U phase: role K does dv tiles 0-1, role Q does 2-3 ----
        {
#pragma unroll
            for (int s2 = 0; s2 < 2; s2++) {
                const int sj = isQ * 2 + s2;
                f32x4 uu = z4;
                bf16x8 ra0 = ldfrag(RHST, 72, sj * 16, 0, lane);
                uu = __builtin_amdgcn_mfma_f32_16x16x32_bf16(ra0, at0, uu, 0, 0, 0);
                bf16x8 ra1 = ldfrag(RHST, 72, sj * 16, 32, lane);
                uu = __builtin_amdgcn_mfma_f32_16x16x32_bf16(ra1, at1, uu, 0, 0, 0);
#pragma unroll
                for (int r = 0; r < 4; r++) {
                    const int row = sj * 16 + quad * 4 + r;
                    UTp[row * 72 + tW] = f2bf_h(uu[r]);
                    UTk[row * 72 + tW] = f2bf_h(ksc_l * uu[r]);
                }
            }
        }
        block_barrier();   // B3 (UTp/UTk visible)

        // ---- S update: dv-half = role, dk slice = wq ----
        {
#pragma unroll
            for (int i = 0; i < 2; i++)
#pragma unroll
                for (int j = 0; j < 4; j++) Sacc[i][j] *= gL;
            const u16* KTp = KT + wq * 4616;
#pragma unroll
            for (int k0 = 0; k0 < 64; k0 += 32) {
                bf16x8 au[2], bk[4];
#pragma unroll
                for (int i = 0; i < 2; i++) au[i] = ldfrag(UTk, 72, isQ * 32 + i * 16, k0, lane);
#pragma unroll
                for (int j = 0; j < 4; j++)
                    bk[j] = *(const bf16x8*)(KTp + (size_t)(j * 16 + l15) * 72 +
                                             ((k0 + quad * 8 + toff[j]) & 63));
#pragma unroll
                for (int i = 0; i < 2; i++)
#pragma unroll
                    for (int j = 0; j < 4; j++)
                        Sacc[i][j] = __builtin_amdgcn_mfma_f32_16x16x32_bf16(au[i], bk[j], Sacc[i][j], 0, 0, 0);
            }
#pragma unroll
            for (int i = 0; i < 2; i++)
#pragma unroll
                for (int j = 0; j < 4; j++)
#pragma unroll
                    for (int r = 0; r < 4; r++)
                        ST[(isQ * 32 + i * 16 + quad * 4 + r) * 264 + wq * 64 + j * 16 + l15] = f2bf_h(Sacc[i][j][r]);
        }
        block_barrier();   // B4 (ST visible for next chunk)
    };

#pragma unroll 1
    for (int c = 0; c < 64; c += 2) {
        body(F0, F1, c);
        body(F1, F0, c + 1);
    }

    // ---- final deferred O (chunk 63, Q-role) ----
    if (isQ) {
#pragma unroll
        for (int sj = 0; sj < 4; sj++) {
            bf16x8 ua0 = ldfrag(UTp, 72, sj * 16, 0, lane);
            oaccP[sj] = __builtin_amdgcn_mfma_f32_16x16x32_bf16(ua0, amP0, oaccP[sj], 0, 0, 0);
            bf16x8 ua1 = ldfrag(UTp, 72, sj * 16, 32, lane);
            oaccP[sj] = __builtin_amdgcn_mfma_f32_16x16x32_bf16(ua1, amP1, oaccP[sj], 0, 0, 0);
        }
#pragma unroll
        for (int sj = 0; sj < 4; sj++) {
            u16x4 o4;
#pragma unroll
            for (int r = 0; r < 4; r++) o4[r] = f2bf_h(oaccP[sj][r]);
            *(u16x4*)(Ob + obP + sj * 16 + quad * 4) = o4;
        }
    }
}

// ---------------------------------------------------------------------------
// Gated RMSNorm + SiLU; writes og IN PLACE into G.
// ---------------------------------------------------------------------------
__global__ __launch_bounds__(256) void gate_norm_kernel(const u16* __restrict__ O,
                                                        u16* __restrict__ G,
                                                        const float* __restrict__ norm_w) {
    const long row = blockIdx.x >> 2;
    const int h = blockIdx.x & 3;
    const int dv = threadIdx.x;
    const long idx = row * 1024 + h * 256 + dv;
    float o = bf2f(O[idx]);
    float s = o * o;
#pragma unroll
    for (int off = 32; off; off >>= 1) s += __shfl_xor(s, off, 64);
    __shared__ float wsum[4];
    if ((dv & 63) == 0) wsum[dv >> 6] = s;
    __syncthreads();
    const float tot = wsum[0] + wsum[1] + wsum[2] + wsum[3];
    const float r = rsqrtf(tot * (1.f / 256.f) + 1e-5f);
    const float g = bf2f(G[idx]);
    const float val = o * r * norm_w[dv] * (g / (1.f + expf(-g)));
    G[idx] = f2bf(val);
}

// ---------------------------------------------------------------------------
extern "C" void kernel_launch(void* const* d_in, const int* in_sizes, int n_in,
                              void* d_out, int out_size, void* d_ws, size_t ws_size,
                              hipStream_t stream) {
    const float* x       = (const float*)d_in[0];
    const float* Wq      = (const float*)d_in[1];
    const float* Wk      = (const float*)d_in[2];
    const float* Wv      = (const float*)d_in[3];
    const float* Wb      = (const float*)d_in[4];
    const float* Wa      = (const float*)d_in[5];
    const float* A_log   = (const float*)d_in[6];
    const float* dt_bias = (const float*)d_in[7];
    const float* Wg      = (const float*)d_in[8];
    const float* norm_w  = (const float*)d_in[9];
    const float* Wo      = (const float*)d_in[10];

    // workspace: identical 171 MB footprint as previous rounds (proven to fit).
    char* p = (char*)d_ws;
    u16*   WT   = (u16*)p;   p += (size_t)5120 * 1024 * 2;   // WqT|WkT|WvT|WgT|WoT bf16
    u16*   Y    = (u16*)p;   p += (size_t)16384 * 3072 * 2;  // q|k|v bf16
    u16*   G    = (u16*)p;   p += (size_t)16384 * 1024 * 2;  // T|M (prep+scan), then gate/og
    u16*   XO   = (u16*)p;   p += (size_t)16384 * 1024 * 2;  // xb (early), O (scan output)
    float* beta = (float*)p; p += (size_t)16384 * 4 * 4;
    float* dec  = (float*)p; p += (size_t)16384 * 4 * 4;

    u16* Tg = G;                                  // [16*64][64*64] bf16, 8.4 MB
    u16* Mg = G + (size_t)1024 * 4096;            // same, next 8.4 MB
    // sfg (1 MB) overlays WqT, which is dead after the big QKV GEMM.
    float* sfg = (float*)WT;                      // [16*64][256] f32

    cvt_kernel<<<16384, 256, 0, stream>>>(x, XO);

    dim3 tb(32, 8), tg(32, 32);
    transpose_kernel<<<tg, tb, 0, stream>>>(Wq, WT + (size_t)0 * 1024 * 1024);
    transpose_kernel<<<tg, tb, 0, stream>>>(Wk, WT + (size_t)1 * 1024 * 1024);
    transpose_kernel<<<tg, tb, 0, stream>>>(Wv, WT + (size_t)2 * 1024 * 1024);
    transpose_kernel<<<tg, tb, 0, stream>>>(Wg, WT + (size_t)3 * 1024 * 1024);
    transpose_kernel<<<tg, tb, 0, stream>>>(Wo, WT + (size_t)4 * 1024 * 1024);

    // Y = xb @ [Wq|Wk|Wv]   (M=16384, N=3072, K=1024)
    gemm_kernel<0><<<dim3(3072 / 128, 16384 / 128), 256, 0, stream>>>(
        XO, WT, (void*)Y, 16384, 3072, 1024, 3072);

    norm_beta_kernel<<<16384, 1024, 0, stream>>>(XO, Y, Wb, Wa, A_log, dt_bias, beta, dec);

    // prep also writes sfg into the dead WqT region
    prep_kernel<<<1024, 256, 0, stream>>>(Y, beta, dec, Tg, Mg, sfg);

    // xb dead; scan writes O into XO
    scan_kernel<<<64, 512, 0, stream>>>(Y, sfg, Tg, Mg, XO);

    // gate = x @ Wg (fp32 A read directly; overwrites T/M region -> after scan)
    gemm_a32_kernel<<<dim3(1024 / 128, 16384 / 128), 256, 0, stream>>>(
        x, WT + (size_t)3072 * 1024, G, 16384, 1024, 1024, 1024);

    gate_norm_kernel<<<16384 * 4, 256, 0, stream>>>(XO, G, norm_w);

    // out = og @ Wo   (fp32 out)
    gemm_kernel<1><<<dim3(1024 / 128, 16384 / 128), 256, 0, stream>>>(
        G, WT + (size_t)4096 * 1024, d_out, 16384, 1024, 1024, 1024);
}